// Round 8
// baseline (114.194 us; speedup 1.0000x reference)
//
#include <hip/hip_runtime.h>

#define NHEAD 12
#define EMB 768
#define HDD 64
#define SEQ 2048

typedef __attribute__((ext_vector_type(4))) float f32x4;
typedef __attribute__((ext_vector_type(8))) short short8;
typedef __attribute__((ext_vector_type(4))) short short4v;
typedef unsigned int u32;

#define GLL16(g, l)                                                            \
    __builtin_amdgcn_global_load_lds(                                          \
        (const __attribute__((address_space(1))) u32*)(g),                     \
        (__attribute__((address_space(3))) u32*)(l), 16, 0, 0)

static __device__ __forceinline__ short bf16s(float f) {
    unsigned u = __builtin_bit_cast(unsigned, f);
    u = (u + 0x7fffu + ((u >> 16) & 1u)) >> 16;
    return (short)u;
}

// ---- x f32 -> bf16 (row-major [4096][768]) ----
__global__ void k_cvt_x(const float* __restrict__ x, short* __restrict__ xb) {
    const int i = (blockIdx.x * 256 + threadIdx.x) * 8;
    const f32x4* s = (const f32x4*)(x + i);
    f32x4 a = s[0], b = s[1];
    short8 o;
    o[0] = bf16s(a[0]); o[1] = bf16s(a[1]); o[2] = bf16s(a[2]); o[3] = bf16s(a[3]);
    o[4] = bf16s(b[0]); o[5] = bf16s(b[1]); o[6] = bf16s(b[2]); o[7] = bf16s(b[3]);
    *(short8*)(xb + i) = o;
}

// ---- Wq/Wk/Wv [12][768][64] f32 -> Wt[(h*64+d)][768 e] bf16 (z picks q/k/v) ----
__global__ void k_cvt_whead(const float* __restrict__ Wq, const float* __restrict__ Wk,
                            const float* __restrict__ Wv, short* __restrict__ WqT,
                            short* __restrict__ WkT, short* __restrict__ WvT) {
    const float* W = blockIdx.z == 0 ? Wq : (blockIdx.z == 1 ? Wk : Wv);
    short* Wt = blockIdx.z == 0 ? WqT : (blockIdx.z == 1 ? WkT : WvT);
    __shared__ float tile[64][65];
    const int h = blockIdx.x, e0 = blockIdx.y * 64;
    const int t = threadIdx.x;
    const int r = t >> 2, c0 = (t & 3) * 16;
    const float* src = W + (h * EMB + e0 + r) * HDD + c0;
#pragma unroll
    for (int i = 0; i < 16; ++i) tile[r][c0 + i] = src[i];
    __syncthreads();
    short* dst = Wt + (h * HDD + r) * EMB + e0 + c0;  // r acts as d here
#pragma unroll
    for (int i = 0; i < 16; ++i) dst[i] = bf16s(tile[c0 + i][r]);
}

// ---- Wo [768 k][768 n] f32 -> WoT[n][k] bf16 ----
__global__ void k_cvt_wo(const float* __restrict__ W, short* __restrict__ Wt) {
    __shared__ float tile[64][65];
    const int k0 = blockIdx.x * 64, n0 = blockIdx.y * 64;
    const int t = threadIdx.x;
    const int r = t >> 2, c0 = (t & 3) * 16;
    const float* src = W + (k0 + r) * EMB + n0 + c0;
#pragma unroll
    for (int i = 0; i < 16; ++i) tile[r][c0 + i] = src[i];
    __syncthreads();
    short* dst = Wt + (n0 + r) * EMB + k0 + c0;
#pragma unroll
    for (int i = 0; i < 16; ++i) dst[i] = bf16s(tile[c0 + i][r]);
}

// ---- GEMM: C[m][n] = sum_k A[m][k]*Bt[n][k], K=768, BK=64, T2 xor-swizzle.
// Swizzle discipline (rule #21): LDS dest linear (global_load_lds), global
// SOURCE col pre-swizzled ((lane&7)^(lane>>3))*8, READ applies same XOR.
// MODE 0: z=0 -> Q*0.125 scattered [B,H,S,D]; z=1 -> K scattered;
//         z=2 -> A/B swapped, out = V^T [B,H,D,S] (coalesced).
// MODE 1: f32 out row-major [m][768] + bias.
#define GBK 64
template <int MODE>
__global__ __launch_bounds__(256) void k_gemm(
        const short* __restrict__ xb, const short* __restrict__ Wt0,
        const short* __restrict__ Wt1, const short* __restrict__ Wt2,
        short* __restrict__ Qo, short* __restrict__ Ko, short* __restrict__ Vo,
        const float* __restrict__ bias, float* __restrict__ Fout) {
    __shared__ alignas(16) short As[128 * GBK];
    __shared__ alignas(16) short Bs[128 * GBK];
    const int t = threadIdx.x, lane = t & 63, wave = t >> 6;
    const int z = (MODE == 0) ? blockIdx.z : 0;
    const short* Ap;
    const short* Bp;
    int m0, n0;
    if (MODE == 1) {
        Ap = xb; Bp = Wt0; m0 = blockIdx.y * 128; n0 = blockIdx.x * 128;
    } else if (z == 0) {
        Ap = xb; Bp = Wt0; m0 = blockIdx.y * 128; n0 = blockIdx.x * 128;
    } else if (z == 1) {
        Ap = xb; Bp = Wt1; m0 = blockIdx.y * 128; n0 = blockIdx.x * 128;
    } else {  // V^T: A = WvT (768 rows), B = xb (4096 rows)
        Ap = Wt2; Bp = xb; m0 = blockIdx.x * 128; n0 = blockIdx.y * 128;
    }

    // staging: 8 lanes/row (128B), 4 issues cover 32 rows/wave; source col
    // pre-swizzled so linear LDS == swizzled layout
    const int srow = lane >> 3;
    const int scolSw = ((lane & 7) ^ (lane >> 3)) * 8;
    const short* gA = Ap + (long)(m0 + wave * 32 + srow) * EMB + scolSw;
    const short* gB = Bp + (long)(n0 + wave * 32 + srow) * EMB + scolSw;

    const int wm = (wave >> 1) * 64, wn = (wave & 1) * 64;
    const int fr = lane & 15, hi = lane >> 4, fk = hi * 8;
    const int sxa = (fr & 7) << 3;  // read-side XOR (element units)

    f32x4 acc[4][4];
#pragma unroll
    for (int i = 0; i < 4; ++i)
#pragma unroll
        for (int j = 0; j < 4; ++j)
#pragma unroll
            for (int e = 0; e < 4; ++e) acc[i][j][e] = 0.f;

    for (int kk = 0; kk < EMB; kk += GBK) {
        __syncthreads();
#pragma unroll
        for (int i = 0; i < 4; ++i) {
            GLL16(gA + kk + i * 8 * EMB, As + (wave * 32 + i * 8) * GBK);
            GLL16(gB + kk + i * 8 * EMB, Bs + (wave * 32 + i * 8) * GBK);
        }
        __syncthreads();
#pragma unroll
        for (int kc = 0; kc < GBK; kc += 32) {
            short8 af[4], bfq[4];
#pragma unroll
            for (int i = 0; i < 4; ++i)
                af[i] = *(const short8*)(As + (wm + i * 16 + fr) * GBK + ((kc + fk) ^ sxa));
#pragma unroll
            for (int j = 0; j < 4; ++j)
                bfq[j] = *(const short8*)(Bs + (wn + j * 16 + fr) * GBK + ((kc + fk) ^ sxa));
#pragma unroll
            for (int i = 0; i < 4; ++i)
#pragma unroll
                for (int j = 0; j < 4; ++j)
                    acc[i][j] = __builtin_amdgcn_mfma_f32_16x16x32_bf16(af[i], bfq[j], acc[i][j], 0, 0, 0);
        }
    }

    const int r0 = hi * 4;
#pragma unroll
    for (int i = 0; i < 4; ++i) {
#pragma unroll
        for (int j = 0; j < 4; ++j) {
            const int nbase = n0 + wn + j * 16 + fr;
            float bj = 0.f;
            if (MODE == 1) bj = bias[nbase];
#pragma unroll
            for (int r = 0; r < 4; ++r) {
                const int m = m0 + wm + i * 16 + r0 + r;
                float v = acc[i][j][r];
                if (MODE == 0) {
                    if (z == 2) {
                        const int hh = m >> 6, dd = m & 63;
                        const int bb = nbase >> 11, ss = nbase & 2047;
                        Vo[(long)((bb * NHEAD + hh) * HDD + dd) * SEQ + ss] = bf16s(v);
                    } else {
                        const int bb = m >> 11, ss = m & 2047;
                        const int hh = nbase >> 6, dd = nbase & 63;
                        short* Dst = (z == 0) ? Qo : Ko;
                        if (z == 0) v *= 0.125f;  // fold 1/sqrt(64) into Q
                        Dst[(long)((bb * NHEAD + hh) * SEQ + ss) * HDD + dd] = bf16s(v);
                    }
                } else {
                    Fout[(long)m * EMB + nbase] = v + bj;
                }
            }
        }
    }
}

// ---- causal flash attention (swapped-operand form) ----
// Round-8: work-balanced pairing — each block processes q-strips {15-p, p}
// = exactly 34 tiles; 192 equal blocks. 8 waves x 16 q-rows, double-buffered
// K/V, one barrier/tile, P packed to ds_write_b64.
// Q,K: [B,H,S,64] bf16 (Q pre-scaled by 0.125); VT: [B,H,64,S] -> O [B,S,768] bf16
__global__ __launch_bounds__(512) void k_attn(
        const short* __restrict__ Q, const short* __restrict__ K,
        const short* __restrict__ VT, short* __restrict__ O) {
    __shared__ alignas(16) short Kbuf[2][64 * 72];   // [key][d]
    __shared__ alignas(16) short Vbuf[2][64 * 72];   // [d][key]
    __shared__ alignas(16) short Ps[8][16 * 72];     // per-wave P[q][key]; reused as O buf
    const int bh = blockIdx.x;
    const int h = bh % NHEAD, b = bh / NHEAD;
    const int pairp = blockIdx.y;  // 0..7
    const int t = threadIdx.x, lane = t & 63, wave = t >> 6;
    const long base = (long)(b * NHEAD + h) * SEQ * HDD;
    const short* Qg = Q + base;
    const short* Kg = K + base;
    const short* Vg = VT + base;  // [64][2048]
    const int fr = lane & 15, hi = lane >> 4, fk = hi * 8, r0 = hi * 4;
    const int srow = t >> 3, scol = (t & 7) * 8;
    const short* KgS = Kg + (long)srow * HDD + scol;
    const short* VgS = Vg + (long)srow * SEQ + scol;
    short* Pw = &Ps[wave][0];
    short* Os = &Ps[0][0];

#pragma unroll
    for (int ph = 0; ph < 2; ++ph) {
        const int qs = ph == 0 ? 15 - pairp : pairp;
        const int q0 = qs * 128;
        const int ntile = 2 * qs + 2;
        const int wq = q0 + wave * 16;  // this wave's 16 q-rows

        short8 qf[2];
#pragma unroll
        for (int c = 0; c < 2; ++c)
            qf[c] = *(const short8*)(Qg + (long)(wq + fr) * HDD + c * 32 + fk);

        f32x4 oacc[4];  // O^T: row d = dt*16+r0+r, col q = fr
#pragma unroll
        for (int i = 0; i < 4; ++i)
#pragma unroll
            for (int e = 0; e < 4; ++e) oacc[i][e] = 0.f;
        float mrun = -3e38f, lrun = 0.f;

        // prologue: tile 0 -> buf0; prefetch tile 1 into regs
        short8 kvR = *(const short8*)(KgS);
        short8 vvR = *(const short8*)(VgS);
        *(short8*)(&Kbuf[0][srow * 72 + scol]) = kvR;
        *(short8*)(&Vbuf[0][srow * 72 + scol]) = vvR;
        if (ntile > 1) {
            kvR = *(const short8*)(KgS + (long)64 * HDD);
            vvR = *(const short8*)(VgS + 64);
        }
        __syncthreads();

        for (int kt = 0; kt < ntile; ++kt) {
            const int k0 = kt * 64;
            const int cur = kt & 1;
            if (kt + 1 < ntile) {
                *(short8*)(&Kbuf[cur ^ 1][srow * 72 + scol]) = kvR;
                *(short8*)(&Vbuf[cur ^ 1][srow * 72 + scol]) = vvR;
                if (kt + 2 < ntile) {
                    kvR = *(const short8*)(KgS + (long)(k0 + 128) * HDD);
                    vvR = *(const short8*)(VgS + (k0 + 128));
                }
            }
            if (k0 <= wq + 15) {  // wave-uniform activity guard
                const short* Ks = &Kbuf[cur][0];
                const short* Vs = &Vbuf[cur][0];

                f32x4 st[4];
#pragma unroll
                for (int nt = 0; nt < 4; ++nt) {
                    const short8 kf0 = *(const short8*)(Ks + (nt * 16 + fr) * 72 + fk);
                    const short8 kf1 = *(const short8*)(Ks + (nt * 16 + fr) * 72 + 32 + fk);
#pragma unroll
                    for (int e = 0; e < 4; ++e) st[nt][e] = 0.f;
                    st[nt] = __builtin_amdgcn_mfma_f32_16x16x32_bf16(kf0, qf[0], st[nt], 0, 0, 0);
                    st[nt] = __builtin_amdgcn_mfma_f32_16x16x32_bf16(kf1, qf[1], st[nt], 0, 0, 0);
                }

                float p[4][4];
                float pmax = -3e38f;
                if (k0 + 63 > wq) {  // diagonal-overlap tile: causal mask
                    const int myq = wq + fr;
#pragma unroll
                    for (int nt = 0; nt < 4; ++nt)
#pragma unroll
                        for (int r = 0; r < 4; ++r) {
                            float s = st[nt][r];
                            if (k0 + nt * 16 + r0 + r > myq) s = -3e38f;
                            p[nt][r] = s;
                            pmax = fmaxf(pmax, s);
                        }
                } else {
#pragma unroll
                    for (int nt = 0; nt < 4; ++nt)
#pragma unroll
                        for (int r = 0; r < 4; ++r) {
                            p[nt][r] = st[nt][r];
                            pmax = fmaxf(pmax, st[nt][r]);
                        }
                }
                pmax = fmaxf(pmax, __shfl_xor(pmax, 16, 64));
                pmax = fmaxf(pmax, __shfl_xor(pmax, 32, 64));
                const float mnew = fmaxf(mrun, pmax);
                const float corr = __expf(mrun - mnew);
                mrun = mnew;
                float rsum = 0.f;
#pragma unroll
                for (int nt = 0; nt < 4; ++nt)
#pragma unroll
                    for (int r = 0; r < 4; ++r) {
                        const float e = __expf(p[nt][r] - mnew);
                        p[nt][r] = e;
                        rsum += e;
                    }
                rsum += __shfl_xor(rsum, 16, 64);
                rsum += __shfl_xor(rsum, 32, 64);
                lrun = lrun * corr + rsum;
#pragma unroll
                for (int dt = 0; dt < 4; ++dt)
#pragma unroll
                    for (int e = 0; e < 4; ++e) oacc[dt][e] *= corr;

                // P[q][key] -> per-wave LDS, packed b64 (4 contiguous cols)
#pragma unroll
                for (int nt = 0; nt < 4; ++nt) {
                    short4v pk;
                    pk[0] = bf16s(p[nt][0]);
                    pk[1] = bf16s(p[nt][1]);
                    pk[2] = bf16s(p[nt][2]);
                    pk[3] = bf16s(p[nt][3]);
                    *(short4v*)(Pw + fr * 72 + nt * 16 + r0) = pk;
                }

                // O^T += V^T P^T
#pragma unroll
                for (int kc = 0; kc < 2; ++kc) {
                    const short8 pf = *(const short8*)(Pw + fr * 72 + kc * 32 + fk);
#pragma unroll
                    for (int dt = 0; dt < 4; ++dt) {
                        const short8 vf = *(const short8*)(Vs + (dt * 16 + fr) * 72 + kc * 32 + fk);
                        oacc[dt] = __builtin_amdgcn_mfma_f32_16x16x32_bf16(vf, pf, oacc[dt], 0, 0, 0);
                    }
                }
            }
            __syncthreads();  // buf[cur^1] writes visible; buf[cur] reads done
        }

        // transpose O^T back via LDS (Ps reused as flat [128][72]) and store
        const float iv = 1.0f / lrun;
#pragma unroll
        for (int dt = 0; dt < 4; ++dt)
#pragma unroll
            for (int r = 0; r < 4; ++r)
                Os[(wave * 16 + fr) * 72 + dt * 16 + r0 + r] = bf16s(oacc[dt][r] * iv);
        __syncthreads();
        {
            const int row = t >> 2, c0 = (t & 3) * 16;
            const short8 o0 = *(const short8*)(Os + row * 72 + c0);
            const short8 o1 = *(const short8*)(Os + row * 72 + c0 + 8);
            short* Og = O + (long)(b * SEQ + q0 + row) * EMB + h * HDD + c0;
            *(short8*)Og = o0;
            *(short8*)(Og + 8) = o1;
        }
        __syncthreads();  // Os reads done before next phase's P writes
    }
}

extern "C" void kernel_launch(void* const* d_in, const int* in_sizes, int n_in,
                              void* d_out, int out_size, void* d_ws, size_t ws_size,
                              hipStream_t stream) {
    const float* x  = (const float*)d_in[0];
    const float* Wq = (const float*)d_in[1];
    const float* Wk = (const float*)d_in[2];
    const float* Wv = (const float*)d_in[3];
    const float* Wo = (const float*)d_in[4];
    const float* bo = (const float*)d_in[5];
    float* out = (float*)d_out;

    char* ws = (char*)d_ws;
    short* xb  = (short*)(ws + 0);         // 4096x768 bf16
    short* WqT = (short*)(ws + 6291456);
    short* WkT = (short*)(ws + 7471104);
    short* WvT = (short*)(ws + 8650752);
    short* WoT = (short*)(ws + 9830400);
    short* Qb  = (short*)(ws + 11010048);  // [2,12,2048,64] bf16 (pre-scaled)
    short* Kb  = (short*)(ws + 17301504);  // [2,12,2048,64]
    short* VTb = (short*)(ws + 23592960);  // [2,12,64,2048] (transposed)
    short* Ob  = (short*)(ws + 29884416);  // [4096,768] bf16

    k_cvt_x<<<dim3(1536), dim3(256), 0, stream>>>(x, xb);
    k_cvt_whead<<<dim3(12, 12, 3), dim3(256), 0, stream>>>(Wq, Wk, Wv, WqT, WkT, WvT);
    k_cvt_wo<<<dim3(12, 12), dim3(256), 0, stream>>>(Wo, WoT);
    k_gemm<0><<<dim3(6, 32, 3), dim3(256), 0, stream>>>(
        xb, WqT, WkT, WvT, Qb, Kb, VTb, (const float*)nullptr, (float*)nullptr);
    k_attn<<<dim3(24, 8), dim3(512), 0, stream>>>(Qb, Kb, VTb, Ob);
    k_gemm<1><<<dim3(6, 32, 1), dim3(256), 0, stream>>>(
        Ob, WoT, (const short*)nullptr, (const short*)nullptr,
        (short*)nullptr, (short*)nullptr, (short*)nullptr, bo, out);
}

// Round 9
// 112.917 us; speedup vs baseline: 1.0113x; 1.0113x over previous
//
#include <hip/hip_runtime.h>

#define NHEAD 12
#define EMB 768
#define HDD 64
#define SEQ 2048

typedef __attribute__((ext_vector_type(4))) float f32x4;
typedef __attribute__((ext_vector_type(8))) short short8;
typedef __attribute__((ext_vector_type(4))) short short4v;
typedef unsigned int u32;

#define GLL16(g, l)                                                            \
    __builtin_amdgcn_global_load_lds(                                          \
        (const __attribute__((address_space(1))) u32*)(g),                     \
        (__attribute__((address_space(3))) u32*)(l), 16, 0, 0)

static __device__ __forceinline__ short bf16s(float f) {
    unsigned u = __builtin_bit_cast(unsigned, f);
    u = (u + 0x7fffu + ((u >> 16) & 1u)) >> 16;
    return (short)u;
}

// ---- x f32 -> bf16 (row-major [4096][768]) ----
__global__ void k_cvt_x(const float* __restrict__ x, short* __restrict__ xb) {
    const int i = (blockIdx.x * 256 + threadIdx.x) * 8;
    const f32x4* s = (const f32x4*)(x + i);
    f32x4 a = s[0], b = s[1];
    short8 o;
    o[0] = bf16s(a[0]); o[1] = bf16s(a[1]); o[2] = bf16s(a[2]); o[3] = bf16s(a[3]);
    o[4] = bf16s(b[0]); o[5] = bf16s(b[1]); o[6] = bf16s(b[2]); o[7] = bf16s(b[3]);
    *(short8*)(xb + i) = o;
}

// ---- Wq/Wk/Wv [12][768][64] f32 -> Wt[(h*64+d)][768 e] bf16 (z picks q/k/v) ----
__global__ void k_cvt_whead(const float* __restrict__ Wq, const float* __restrict__ Wk,
                            const float* __restrict__ Wv, short* __restrict__ WqT,
                            short* __restrict__ WkT, short* __restrict__ WvT) {
    const float* W = blockIdx.z == 0 ? Wq : (blockIdx.z == 1 ? Wk : Wv);
    short* Wt = blockIdx.z == 0 ? WqT : (blockIdx.z == 1 ? WkT : WvT);
    __shared__ float tile[64][65];
    const int h = blockIdx.x, e0 = blockIdx.y * 64;
    const int t = threadIdx.x;
    const int r = t >> 2, c0 = (t & 3) * 16;
    const float* src = W + (h * EMB + e0 + r) * HDD + c0;
#pragma unroll
    for (int i = 0; i < 16; ++i) tile[r][c0 + i] = src[i];
    __syncthreads();
    short* dst = Wt + (h * HDD + r) * EMB + e0 + c0;  // r acts as d here
#pragma unroll
    for (int i = 0; i < 16; ++i) dst[i] = bf16s(tile[c0 + i][r]);
}

// ---- Wo [768 k][768 n] f32 -> WoT[n][k] bf16 ----
__global__ void k_cvt_wo(const float* __restrict__ W, short* __restrict__ Wt) {
    __shared__ float tile[64][65];
    const int k0 = blockIdx.x * 64, n0 = blockIdx.y * 64;
    const int t = threadIdx.x;
    const int r = t >> 2, c0 = (t & 3) * 16;
    const float* src = W + (k0 + r) * EMB + n0 + c0;
#pragma unroll
    for (int i = 0; i < 16; ++i) tile[r][c0 + i] = src[i];
    __syncthreads();
    short* dst = Wt + (n0 + r) * EMB + k0 + c0;
#pragma unroll
    for (int i = 0; i < 16; ++i) dst[i] = bf16s(tile[c0 + i][r]);
}

// ---- GEMM (r7-proven m97 structure): C[m][n] = sum_k A[m][k]*Bt[n][k], BK=32.
// MODE 0: z=0 -> Q*0.125 scattered [B,H,S,D]; z=1 -> K scattered;
//         z=2 -> A/B swapped, out = V^T [B,H,D,S] (coalesced).
// MODE 1: f32 out row-major [m][768] + bias.
template <int MODE>
__global__ __launch_bounds__(256) void k_gemm(
        const short* __restrict__ xb, const short* __restrict__ Wt0,
        const short* __restrict__ Wt1, const short* __restrict__ Wt2,
        short* __restrict__ Qo, short* __restrict__ Ko, short* __restrict__ Vo,
        const float* __restrict__ bias, float* __restrict__ Fout) {
    __shared__ alignas(16) short As[128 * 32];
    __shared__ alignas(16) short Bs[128 * 32];
    const int t = threadIdx.x, lane = t & 63, wave = t >> 6;
    const int z = (MODE == 0) ? blockIdx.z : 0;
    const short* Ap;
    const short* Bp;
    int m0, n0;
    if (MODE == 1) {
        Ap = xb; Bp = Wt0; m0 = blockIdx.y * 128; n0 = blockIdx.x * 128;
    } else if (z == 0) {
        Ap = xb; Bp = Wt0; m0 = blockIdx.y * 128; n0 = blockIdx.x * 128;
    } else if (z == 1) {
        Ap = xb; Bp = Wt1; m0 = blockIdx.y * 128; n0 = blockIdx.x * 128;
    } else {  // V^T: A = WvT (768 rows), B = xb (4096 rows)
        Ap = Wt2; Bp = xb; m0 = blockIdx.x * 128; n0 = blockIdx.y * 128;
    }

    const short* gA = Ap + (long)(m0 + wave * 32 + (lane >> 2)) * EMB + (lane & 3) * 8;
    const short* gB = Bp + (long)(n0 + wave * 32 + (lane >> 2)) * EMB + (lane & 3) * 8;
    short* lA = As + (wave * 32) * 32;
    short* lB = Bs + (wave * 32) * 32;

    const int wm = (wave >> 1) * 64, wn = (wave & 1) * 64;
    const int fr = lane & 15, hi = lane >> 4, fk = hi * 8;

    f32x4 acc[4][4];
#pragma unroll
    for (int i = 0; i < 4; ++i)
#pragma unroll
        for (int j = 0; j < 4; ++j)
#pragma unroll
            for (int e = 0; e < 4; ++e) acc[i][j][e] = 0.f;

    for (int kk = 0; kk < EMB; kk += 32) {
        __syncthreads();
        GLL16(gA + kk, lA);
        GLL16(gA + kk + 16 * EMB, lA + 16 * 32);
        GLL16(gB + kk, lB);
        GLL16(gB + kk + 16 * EMB, lB + 16 * 32);
        __syncthreads();
        short8 af[4], bfq[4];
#pragma unroll
        for (int i = 0; i < 4; ++i)
            af[i] = *(const short8*)(As + (wm + i * 16 + fr) * 32 + fk);
#pragma unroll
        for (int j = 0; j < 4; ++j)
            bfq[j] = *(const short8*)(Bs + (wn + j * 16 + fr) * 32 + fk);
#pragma unroll
        for (int i = 0; i < 4; ++i)
#pragma unroll
            for (int j = 0; j < 4; ++j)
                acc[i][j] = __builtin_amdgcn_mfma_f32_16x16x32_bf16(af[i], bfq[j], acc[i][j], 0, 0, 0);
    }

    const int r0 = hi * 4;
#pragma unroll
    for (int i = 0; i < 4; ++i) {
#pragma unroll
        for (int j = 0; j < 4; ++j) {
            const int nbase = n0 + wn + j * 16 + fr;
            float bj = 0.f;
            if (MODE == 1) bj = bias[nbase];
#pragma unroll
            for (int r = 0; r < 4; ++r) {
                const int m = m0 + wm + i * 16 + r0 + r;
                float v = acc[i][j][r];
                if (MODE == 0) {
                    if (z == 2) {
                        const int hh = m >> 6, dd = m & 63;
                        const int bb = nbase >> 11, ss = nbase & 2047;
                        Vo[(long)((bb * NHEAD + hh) * HDD + dd) * SEQ + ss] = bf16s(v);
                    } else {
                        const int bb = m >> 11, ss = m & 2047;
                        const int hh = nbase >> 6, dd = nbase & 63;
                        short* Dst = (z == 0) ? Qo : Ko;
                        if (z == 0) v *= 0.125f;  // fold 1/sqrt(64) into Q
                        Dst[(long)((bb * NHEAD + hh) * SEQ + ss) * HDD + dd] = bf16s(v);
                    }
                } else {
                    Fout[(long)m * EMB + nbase] = v + bj;
                }
            }
        }
    }
}

// ---- causal flash attention (swapped-operand form) ----
// Round-9: r7 grid (24,16) longest-first; K/V staged via global_load_lds into
// UNPADDED [64][64] tiles with XOR chunk-swizzle (rule #21: linear LDS dest +
// pre-swizzled global source + same XOR on read). LDS 50KB -> 3 blocks/CU.
// s_setprio(1) around MFMA clusters (T5). P path: per-wave LDS, b64 pack.
// Q,K: [B,H,S,64] bf16 (Q pre-scaled by 0.125); VT: [B,H,64,S] -> O [B,S,768] bf16
__global__ __launch_bounds__(512) void k_attn(
        const short* __restrict__ Q, const short* __restrict__ K,
        const short* __restrict__ VT, short* __restrict__ O) {
    __shared__ alignas(16) short Kbuf[2][64 * 64];   // [key][d], chunk-swizzled
    __shared__ alignas(16) short Vbuf[2][64 * 64];   // [d][key], chunk-swizzled
    __shared__ alignas(16) short Ps[8][16 * 72];     // per-wave P[q][key]; reused as O buf
    const int bh = blockIdx.x;
    const int h = bh % NHEAD, b = bh / NHEAD;
    const int qs = (int)gridDim.y - 1 - (int)blockIdx.y;  // longest first
    const int q0 = qs * 128;
    const int ntile = 2 * qs + 2;
    const int t = threadIdx.x, lane = t & 63, wave = t >> 6;
    const long base = (long)(b * NHEAD + h) * SEQ * HDD;
    const short* Qg = Q + base;
    const short* Kg = K + base;
    const short* Vg = VT + base;  // [64][2048]
    const int fr = lane & 15, hi = lane >> 4, fk = hi * 8, r0 = hi * 4;
    const int wq = q0 + wave * 16;  // this wave's 16 q-rows

    // Q fragments (B-frag, rows = q), resident all kernel
    short8 qf[2];
#pragma unroll
    for (int c = 0; c < 2; ++c)
        qf[c] = *(const short8*)(Qg + (long)(wq + fr) * HDD + c * 32 + fk);

    f32x4 oacc[4];  // O^T: row d = dt*16+r0+r, col q = fr
#pragma unroll
    for (int i = 0; i < 4; ++i)
#pragma unroll
        for (int e = 0; e < 4; ++e) oacc[i][e] = 0.f;
    float mrun = -3e38f, lrun = 0.f;

    // GLL staging: thread t -> LDS 16B chunk t (linear); global source chunk
    // XOR-swizzled so LDS[r][c] = G[r][c ^ (r&7)] (chunks of 8 elements).
    const int srow = t >> 3;
    const int scolSw = ((t & 7) ^ (srow & 7)) * 8;
    const short* KgS = Kg + (long)srow * HDD + scolSw;  // + k0*HDD per tile
    const short* VgS = Vg + (long)srow * SEQ + scolSw;  // + k0 per tile
    const int ldst = wave * 512;  // wave-uniform LDS dest offset (shorts)
    short* Pw = &Ps[wave][0];
    short* Os = &Ps[0][0];
    // read-side swizzle: frag (row, key/d-chunk kc*4+hi) -> LDS chunk ^(row&7)
    const int rx = fr & 7;

    // prologue: tile 0 -> buf0
    GLL16(KgS, &Kbuf[0][ldst]);
    GLL16(VgS, &Vbuf[0][ldst]);
    __syncthreads();  // drains vmcnt

    for (int kt = 0; kt < ntile; ++kt) {
        const int k0 = kt * 64;
        const int cur = kt & 1;
        if (kt + 1 < ntile) {  // async prefetch next tile into other buffer
            GLL16(KgS + (long)(k0 + 64) * HDD, &Kbuf[cur ^ 1][ldst]);
            GLL16(VgS + (k0 + 64), &Vbuf[cur ^ 1][ldst]);
        }
        if (k0 <= wq + 15) {  // wave-uniform activity guard
            const short* Ks = &Kbuf[cur][0];
            const short* Vs = &Vbuf[cur][0];

            // S^T = K Q^T : tile nt covers keys nt*16..+15 (rows), q = fr (col)
            f32x4 st[4];
#pragma unroll
            for (int nt = 0; nt < 4; ++nt) {
                const short8 kf0 = *(const short8*)(Ks + (nt * 16 + fr) * 64 + ((0 + hi) ^ rx) * 8);
                const short8 kf1 = *(const short8*)(Ks + (nt * 16 + fr) * 64 + ((4 + hi) ^ rx) * 8);
#pragma unroll
                for (int e = 0; e < 4; ++e) st[nt][e] = 0.f;
                __builtin_amdgcn_s_setprio(1);
                st[nt] = __builtin_amdgcn_mfma_f32_16x16x32_bf16(kf0, qf[0], st[nt], 0, 0, 0);
                st[nt] = __builtin_amdgcn_mfma_f32_16x16x32_bf16(kf1, qf[1], st[nt], 0, 0, 0);
                __builtin_amdgcn_s_setprio(0);
            }

            // softmax: lane holds 16 keys of one q-row (q = fr)
            float p[4][4];
            float pmax = -3e38f;
            if (k0 + 63 > wq) {  // diagonal-overlap tile: causal mask
                const int myq = wq + fr;
#pragma unroll
                for (int nt = 0; nt < 4; ++nt)
#pragma unroll
                    for (int r = 0; r < 4; ++r) {
                        float s = st[nt][r];
                        if (k0 + nt * 16 + r0 + r > myq) s = -3e38f;
                        p[nt][r] = s;
                        pmax = fmaxf(pmax, s);
                    }
            } else {
#pragma unroll
                for (int nt = 0; nt < 4; ++nt)
#pragma unroll
                    for (int r = 0; r < 4; ++r) {
                        p[nt][r] = st[nt][r];
                        pmax = fmaxf(pmax, st[nt][r]);
                    }
            }
            pmax = fmaxf(pmax, __shfl_xor(pmax, 16, 64));
            pmax = fmaxf(pmax, __shfl_xor(pmax, 32, 64));
            const float mnew = fmaxf(mrun, pmax);
            const float corr = __expf(mrun - mnew);
            mrun = mnew;
            float rsum = 0.f;
#pragma unroll
            for (int nt = 0; nt < 4; ++nt)
#pragma unroll
                for (int r = 0; r < 4; ++r) {
                    const float e = __expf(p[nt][r] - mnew);
                    p[nt][r] = e;
                    rsum += e;
                }
            rsum += __shfl_xor(rsum, 16, 64);
            rsum += __shfl_xor(rsum, 32, 64);
            lrun = lrun * corr + rsum;
#pragma unroll
            for (int dt = 0; dt < 4; ++dt)
#pragma unroll
                for (int e = 0; e < 4; ++e) oacc[dt][e] *= corr;

            // P[q][key] -> per-wave LDS, packed b64 (4 contiguous cols)
#pragma unroll
            for (int nt = 0; nt < 4; ++nt) {
                short4v pk;
                pk[0] = bf16s(p[nt][0]);
                pk[1] = bf16s(p[nt][1]);
                pk[2] = bf16s(p[nt][2]);
                pk[3] = bf16s(p[nt][3]);
                *(short4v*)(Pw + fr * 72 + nt * 16 + r0) = pk;
            }

            // O^T += V^T P^T (V rows = d, swizzled key-chunks)
#pragma unroll
            for (int kc = 0; kc < 2; ++kc) {
                const short8 pf = *(const short8*)(Pw + fr * 72 + kc * 32 + fk);
#pragma unroll
                for (int dt = 0; dt < 4; ++dt) {
                    const short8 vf = *(const short8*)(Vs + (dt * 16 + fr) * 64 + ((kc * 4 + hi) ^ rx) * 8);
                    __builtin_amdgcn_s_setprio(1);
                    oacc[dt] = __builtin_amdgcn_mfma_f32_16x16x32_bf16(vf, pf, oacc[dt], 0, 0, 0);
                    __builtin_amdgcn_s_setprio(0);
                }
            }
        }
        __syncthreads();  // prefetch landed; buf[cur] reads done
    }

    // transpose O^T back via LDS (Ps reused as flat [128][72]) and store
    const float iv = 1.0f / lrun;
#pragma unroll
    for (int dt = 0; dt < 4; ++dt)
#pragma unroll
        for (int r = 0; r < 4; ++r)
            Os[(wave * 16 + fr) * 72 + dt * 16 + r0 + r] = bf16s(oacc[dt][r] * iv);
    __syncthreads();
    {
        const int row = t >> 2, c0 = (t & 3) * 16;
        const short8 o0 = *(const short8*)(Os + row * 72 + c0);
        const short8 o1 = *(const short8*)(Os + row * 72 + c0 + 8);
        short* Og = O + (long)(b * SEQ + q0 + row) * EMB + h * HDD + c0;
        *(short8*)Og = o0;
        *(short8*)(Og + 8) = o1;
    }
}

extern "C" void kernel_launch(void* const* d_in, const int* in_sizes, int n_in,
                              void* d_out, int out_size, void* d_ws, size_t ws_size,
                              hipStream_t stream) {
    const float* x  = (const float*)d_in[0];
    const float* Wq = (const float*)d_in[1];
    const float* Wk = (const float*)d_in[2];
    const float* Wv = (const float*)d_in[3];
    const float* Wo = (const float*)d_in[4];
    const float* bo = (const float*)d_in[5];
    float* out = (float*)d_out;

    char* ws = (char*)d_ws;
    short* xb  = (short*)(ws + 0);         // 4096x768 bf16
    short* WqT = (short*)(ws + 6291456);
    short* WkT = (short*)(ws + 7471104);
    short* WvT = (short*)(ws + 8650752);
    short* WoT = (short*)(ws + 9830400);
    short* Qb  = (short*)(ws + 11010048);  // [2,12,2048,64] bf16 (pre-scaled)
    short* Kb  = (short*)(ws + 17301504);  // [2,12,2048,64]
    short* VTb = (short*)(ws + 23592960);  // [2,12,64,2048] (transposed)
    short* Ob  = (short*)(ws + 29884416);  // [4096,768] bf16

    k_cvt_x<<<dim3(1536), dim3(256), 0, stream>>>(x, xb);
    k_cvt_whead<<<dim3(12, 12, 3), dim3(256), 0, stream>>>(Wq, Wk, Wv, WqT, WkT, WvT);
    k_cvt_wo<<<dim3(12, 12), dim3(256), 0, stream>>>(Wo, WoT);
    k_gemm<0><<<dim3(6, 32, 3), dim3(256), 0, stream>>>(
        xb, WqT, WkT, WvT, Qb, Kb, VTb, (const float*)nullptr, (float*)nullptr);
    k_attn<<<dim3(24, 16), dim3(512), 0, stream>>>(Qb, Kb, VTb, Ob);
    k_gemm<1><<<dim3(6, 32, 1), dim3(256), 0, stream>>>(
        Ob, WoT, (const short*)nullptr, (const short*)nullptr,
        (short*)nullptr, (short*)nullptr, (short*)nullptr, bo, out);
}

// Round 12
// 105.711 us; speedup vs baseline: 1.0802x; 1.0682x over previous
//
#include <hip/hip_runtime.h>

#define NHEAD 12
#define EMB 768
#define HDD 64
#define SEQ 2048

typedef __attribute__((ext_vector_type(4))) float f32x4;
typedef __attribute__((ext_vector_type(8))) short short8;
typedef __attribute__((ext_vector_type(4))) short short4v;
typedef unsigned int u32;

#define GLL16(g, l)                                                            \
    __builtin_amdgcn_global_load_lds(                                          \
        (const __attribute__((address_space(1))) u32*)(g),                     \
        (__attribute__((address_space(3))) u32*)(l), 16, 0, 0)

static __device__ __forceinline__ short bf16s(float f) {
    unsigned u = __builtin_bit_cast(unsigned, f);
    u = (u + 0x7fffu + ((u >> 16) & 1u)) >> 16;
    return (short)u;
}

// ---- x f32 -> bf16 (row-major [4096][768]) ----
__global__ void k_cvt_x(const float* __restrict__ x, short* __restrict__ xb) {
    const int i = (blockIdx.x * 256 + threadIdx.x) * 8;
    const f32x4* s = (const f32x4*)(x + i);
    f32x4 a = s[0], b = s[1];
    short8 o;
    o[0] = bf16s(a[0]); o[1] = bf16s(a[1]); o[2] = bf16s(a[2]); o[3] = bf16s(a[3]);
    o[4] = bf16s(b[0]); o[5] = bf16s(b[1]); o[6] = bf16s(b[2]); o[7] = bf16s(b[3]);
    *(short8*)(xb + i) = o;
}

// ---- Wq/Wk/Wv [12][768][64] f32 -> Wt[(h*64+d)][768 e] bf16 (z picks q/k/v) ----
__global__ void k_cvt_whead(const float* __restrict__ Wq, const float* __restrict__ Wk,
                            const float* __restrict__ Wv, short* __restrict__ WqT,
                            short* __restrict__ WkT, short* __restrict__ WvT) {
    const float* W = blockIdx.z == 0 ? Wq : (blockIdx.z == 1 ? Wk : Wv);
    short* Wt = blockIdx.z == 0 ? WqT : (blockIdx.z == 1 ? WkT : WvT);
    __shared__ float tile[64][65];
    const int h = blockIdx.x, e0 = blockIdx.y * 64;
    const int t = threadIdx.x;
    const int r = t >> 2, c0 = (t & 3) * 16;
    const float* src = W + (h * EMB + e0 + r) * HDD + c0;
#pragma unroll
    for (int i = 0; i < 16; ++i) tile[r][c0 + i] = src[i];
    __syncthreads();
    short* dst = Wt + (h * HDD + r) * EMB + e0 + c0;  // r acts as d here
#pragma unroll
    for (int i = 0; i < 16; ++i) dst[i] = bf16s(tile[c0 + i][r]);
}

// ---- Wo [768 k][768 n] f32 -> WoT[n][k] bf16 ----
__global__ void k_cvt_wo(const float* __restrict__ W, short* __restrict__ Wt) {
    __shared__ float tile[64][65];
    const int k0 = blockIdx.x * 64, n0 = blockIdx.y * 64;
    const int t = threadIdx.x;
    const int r = t >> 2, c0 = (t & 3) * 16;
    const float* src = W + (k0 + r) * EMB + n0 + c0;
#pragma unroll
    for (int i = 0; i < 16; ++i) tile[r][c0 + i] = src[i];
    __syncthreads();
    short* dst = Wt + (n0 + r) * EMB + k0 + c0;
#pragma unroll
    for (int i = 0; i < 16; ++i) dst[i] = bf16s(tile[c0 + i][r]);
}

// ---- GEMM (m97 structure + BK32 chunk swizzle): C[m][n] = sum_k A[m][k]*Bt[n][k].
// Rule #21: LDS dest linear (global_load_lds), global SOURCE chunk pre-XORed
// with (row>>1)&3, READ applies same XOR. Banks repeat every 2 rows at 64B
// row stride -> (row>>1)&3 spreads 8 aliasing rows over 4 chunk slots = 2-way
// (free, m136). Same discipline r8's BK64 swizzle proved on HW.
// MODE 0: z=0 -> Q*0.125 scattered [B,H,S,D]; z=1 -> K scattered;
//         z=2 -> A/B swapped, out = V^T [B,H,D,S] (coalesced).
// MODE 1: f32 out row-major [m][768] + bias.
template <int MODE>
__global__ __launch_bounds__(256) void k_gemm(
        const short* __restrict__ xb, const short* __restrict__ Wt0,
        const short* __restrict__ Wt1, const short* __restrict__ Wt2,
        short* __restrict__ Qo, short* __restrict__ Ko, short* __restrict__ Vo,
        const float* __restrict__ bias, float* __restrict__ Fout) {
    __shared__ alignas(16) short As[128 * 32];
    __shared__ alignas(16) short Bs[128 * 32];
    const int t = threadIdx.x, lane = t & 63, wave = t >> 6;
    const int z = (MODE == 0) ? blockIdx.z : 0;
    const short* Ap;
    const short* Bp;
    int m0, n0;
    if (MODE == 1) {
        Ap = xb; Bp = Wt0; m0 = blockIdx.y * 128; n0 = blockIdx.x * 128;
    } else if (z == 0) {
        Ap = xb; Bp = Wt0; m0 = blockIdx.y * 128; n0 = blockIdx.x * 128;
    } else if (z == 1) {
        Ap = xb; Bp = Wt1; m0 = blockIdx.y * 128; n0 = blockIdx.x * 128;
    } else {  // V^T: A = WvT (768 rows), B = xb (4096 rows)
        Ap = Wt2; Bp = xb; m0 = blockIdx.x * 128; n0 = blockIdx.y * 128;
    }

    // staging: row = lane>>2 (plus +16 for 2nd issue), chunk = lane&3;
    // source chunk ^= (row>>1)&3  ->  LDS[r][c] = G[r][c ^ ((r>>1)&3)].
    // ((16+srow)>>1)&3 == (srow>>1)&3, so one XOR serves both issues.
    const int srow = lane >> 2;
    const int scolSw = ((lane & 3) ^ ((srow >> 1) & 3)) * 8;
    const short* gA = Ap + (long)(m0 + wave * 32 + srow) * EMB + scolSw;
    const short* gB = Bp + (long)(n0 + wave * 32 + srow) * EMB + scolSw;
    short* lA = As + (wave * 32) * 32;
    short* lB = Bs + (wave * 32) * 32;

    const int wm = (wave >> 1) * 64, wn = (wave & 1) * 64;
    const int fr = lane & 15, hi = lane >> 4;
    const int rdoff = (hi ^ ((fr >> 1) & 3)) * 8;  // read-side swizzled chunk

    f32x4 acc[4][4];
#pragma unroll
    for (int i = 0; i < 4; ++i)
#pragma unroll
        for (int j = 0; j < 4; ++j)
#pragma unroll
            for (int e = 0; e < 4; ++e) acc[i][j][e] = 0.f;

    for (int kk = 0; kk < EMB; kk += 32) {
        __syncthreads();
        GLL16(gA + kk, lA);
        GLL16(gA + kk + 16 * EMB, lA + 16 * 32);
        GLL16(gB + kk, lB);
        GLL16(gB + kk + 16 * EMB, lB + 16 * 32);
        __syncthreads();
        short8 af[4], bfq[4];
#pragma unroll
        for (int i = 0; i < 4; ++i)
            af[i] = *(const short8*)(As + (wm + i * 16 + fr) * 32 + rdoff);
#pragma unroll
        for (int j = 0; j < 4; ++j)
            bfq[j] = *(const short8*)(Bs + (wn + j * 16 + fr) * 32 + rdoff);
#pragma unroll
        for (int i = 0; i < 4; ++i)
#pragma unroll
            for (int j = 0; j < 4; ++j)
                acc[i][j] = __builtin_amdgcn_mfma_f32_16x16x32_bf16(af[i], bfq[j], acc[i][j], 0, 0, 0);
    }

    const int r0 = hi * 4;
#pragma unroll
    for (int i = 0; i < 4; ++i) {
#pragma unroll
        for (int j = 0; j < 4; ++j) {
            const int nbase = n0 + wn + j * 16 + fr;
            float bj = 0.f;
            if (MODE == 1) bj = bias[nbase];
#pragma unroll
            for (int r = 0; r < 4; ++r) {
                const int m = m0 + wm + i * 16 + r0 + r;
                float v = acc[i][j][r];
                if (MODE == 0) {
                    if (z == 2) {
                        const int hh = m >> 6, dd = m & 63;
                        const int bb = nbase >> 11, ss = nbase & 2047;
                        Vo[(long)((bb * NHEAD + hh) * HDD + dd) * SEQ + ss] = bf16s(v);
                    } else {
                        const int bb = m >> 11, ss = m & 2047;
                        const int hh = nbase >> 6, dd = nbase & 63;
                        short* Dst = (z == 0) ? Qo : Ko;
                        if (z == 0) v *= 0.125f;  // fold 1/sqrt(64) into Q
                        Dst[(long)((bb * NHEAD + hh) * SEQ + ss) * HDD + dd] = bf16s(v);
                    }
                } else {
                    Fout[(long)m * EMB + nbase] = v + bj;
                }
            }
        }
    }
}

// ---- causal flash attention (swapped-operand form) ----
// Round-12: ALL-PROVEN pieces only. r7 structure (8 waves x 16 q-rows,
// reg-staged dbuf, 2-deep prefetch, one barrier/tile), __shfl_xor reductions
// (r7), b64 P-pack (r8). Permlane asm is BANNED (failure matrix r7-r11:
// present in both fails, absent from all passes).
// Q,K: [B,H,S,64] bf16 (Q pre-scaled by 0.125); VT: [B,H,64,S] -> O [B,S,768] bf16
__global__ __launch_bounds__(512) void k_attn(
        const short* __restrict__ Q, const short* __restrict__ K,
        const short* __restrict__ VT, short* __restrict__ O) {
    __shared__ alignas(16) short Kbuf[2][64 * 72];   // [key][d]
    __shared__ alignas(16) short Vbuf[2][64 * 72];   // [d][key]
    __shared__ alignas(16) short Ps[8][16 * 72];     // per-wave P[q][key]; reused as O buf
    const int bh = blockIdx.x;
    const int h = bh % NHEAD, b = bh / NHEAD;
    const int qs = (int)gridDim.y - 1 - (int)blockIdx.y;  // longest first
    const int q0 = qs * 128;
    const int ntile = 2 * qs + 2;
    const int t = threadIdx.x, lane = t & 63, wave = t >> 6;
    const long base = (long)(b * NHEAD + h) * SEQ * HDD;
    const short* Qg = Q + base;
    const short* Kg = K + base;
    const short* Vg = VT + base;  // [64][2048]
    const int fr = lane & 15, hi = lane >> 4, fk = hi * 8, r0 = hi * 4;
    const int wq = q0 + wave * 16;  // this wave's 16 q-rows

    short8 qf[2];
#pragma unroll
    for (int c = 0; c < 2; ++c)
        qf[c] = *(const short8*)(Qg + (long)(wq + fr) * HDD + c * 32 + fk);

    f32x4 oacc[4];  // O^T: row d = dt*16+r0+r, col q = fr
#pragma unroll
    for (int i = 0; i < 4; ++i)
#pragma unroll
        for (int e = 0; e < 4; ++e) oacc[i][e] = 0.f;
    float mrun = -3e38f, lrun = 0.f;

    // staging: 512 threads, one short8 each for K and V per tile
    const int srow = t >> 3, scol = (t & 7) * 8;
    const short* KgS = Kg + (long)srow * HDD + scol;
    const short* VgS = Vg + (long)srow * SEQ + scol;
    short* Pw = &Ps[wave][0];

    // prologue: tile 0 -> buf0; prefetch tile 1 into regs
    short8 kvR = *(const short8*)(KgS);
    short8 vvR = *(const short8*)(VgS);
    *(short8*)(&Kbuf[0][srow * 72 + scol]) = kvR;
    *(short8*)(&Vbuf[0][srow * 72 + scol]) = vvR;
    if (ntile > 1) {
        kvR = *(const short8*)(KgS + (long)64 * HDD);
        vvR = *(const short8*)(VgS + 64);
    }
    __syncthreads();

    for (int kt = 0; kt < ntile; ++kt) {
        const int k0 = kt * 64;
        const int cur = kt & 1;
        if (kt + 1 < ntile) {
            *(short8*)(&Kbuf[cur ^ 1][srow * 72 + scol]) = kvR;
            *(short8*)(&Vbuf[cur ^ 1][srow * 72 + scol]) = vvR;
            if (kt + 2 < ntile) {  // issue tile kt+2 loads early
                kvR = *(const short8*)(KgS + (long)(k0 + 128) * HDD);
                vvR = *(const short8*)(VgS + (k0 + 128));
            }
        }
        if (k0 <= wq + 15) {  // wave-uniform activity guard
            const short* Ks = &Kbuf[cur][0];
            const short* Vs = &Vbuf[cur][0];

            f32x4 st[4];
#pragma unroll
            for (int nt = 0; nt < 4; ++nt) {
                const short8 kf0 = *(const short8*)(Ks + (nt * 16 + fr) * 72 + fk);
                const short8 kf1 = *(const short8*)(Ks + (nt * 16 + fr) * 72 + 32 + fk);
#pragma unroll
                for (int e = 0; e < 4; ++e) st[nt][e] = 0.f;
                st[nt] = __builtin_amdgcn_mfma_f32_16x16x32_bf16(kf0, qf[0], st[nt], 0, 0, 0);
                st[nt] = __builtin_amdgcn_mfma_f32_16x16x32_bf16(kf1, qf[1], st[nt], 0, 0, 0);
            }

            float p[4][4];
            float pmax = -3e38f;
            if (k0 + 63 > wq) {  // diagonal-overlap tile: causal mask
                const int myq = wq + fr;
#pragma unroll
                for (int nt = 0; nt < 4; ++nt)
#pragma unroll
                    for (int r = 0; r < 4; ++r) {
                        float s = st[nt][r];
                        if (k0 + nt * 16 + r0 + r > myq) s = -3e38f;
                        p[nt][r] = s;
                        pmax = fmaxf(pmax, s);
                    }
            } else {
#pragma unroll
                for (int nt = 0; nt < 4; ++nt)
#pragma unroll
                    for (int r = 0; r < 4; ++r) {
                        p[nt][r] = st[nt][r];
                        pmax = fmaxf(pmax, st[nt][r]);
                    }
            }
            pmax = fmaxf(pmax, __shfl_xor(pmax, 16, 64));
            pmax = fmaxf(pmax, __shfl_xor(pmax, 32, 64));
            const float mnew = fmaxf(mrun, pmax);
            const float corr = __expf(mrun - mnew);
            mrun = mnew;
            float rsum = 0.f;
#pragma unroll
            for (int nt = 0; nt < 4; ++nt)
#pragma unroll
                for (int r = 0; r < 4; ++r) {
                    const float e = __expf(p[nt][r] - mnew);
                    p[nt][r] = e;
                    rsum += e;
                }
            rsum += __shfl_xor(rsum, 16, 64);
            rsum += __shfl_xor(rsum, 32, 64);
            lrun = lrun * corr + rsum;
#pragma unroll
            for (int dt = 0; dt < 4; ++dt)
#pragma unroll
                for (int e = 0; e < 4; ++e) oacc[dt][e] *= corr;

            // P[q][key] -> per-wave LDS, packed b64 (4 contiguous cols)
#pragma unroll
            for (int nt = 0; nt < 4; ++nt) {
                short4v pk;
                pk[0] = bf16s(p[nt][0]);
                pk[1] = bf16s(p[nt][1]);
                pk[2] = bf16s(p[nt][2]);
                pk[3] = bf16s(p[nt][3]);
                *(short4v*)(Pw + fr * 72 + nt * 16 + r0) = pk;
            }

            // O^T += V^T P^T
#pragma unroll
            for (int kc = 0; kc < 2; ++kc) {
                const short8 pf = *(const short8*)(Pw + fr * 72 + kc * 32 + fk);
#pragma unroll
                for (int dt = 0; dt < 4; ++dt) {
                    const short8 vf = *(const short8*)(Vs + (dt * 16 + fr) * 72 + kc * 32 + fk);
                    oacc[dt] = __builtin_amdgcn_mfma_f32_16x16x32_bf16(vf, pf, oacc[dt], 0, 0, 0);
                }
            }
        }
        __syncthreads();  // buf[cur^1] writes visible; buf[cur] reads done
    }

    // transpose O^T back via LDS (Ps reused as flat [128][72]) and store
    short* Os = &Ps[0][0];
    const float iv = 1.0f / lrun;
#pragma unroll
    for (int dt = 0; dt < 4; ++dt)
#pragma unroll
        for (int r = 0; r < 4; ++r)
            Os[(wave * 16 + fr) * 72 + dt * 16 + r0 + r] = bf16s(oacc[dt][r] * iv);
    __syncthreads();
    {
        const int row = t >> 2, c0 = (t & 3) * 16;
        const short8 o0 = *(const short8*)(Os + row * 72 + c0);
        const short8 o1 = *(const short8*)(Os + row * 72 + c0 + 8);
        short* Og = O + (long)(b * SEQ + q0 + row) * EMB + h * HDD + c0;
        *(short8*)Og = o0;
        *(short8*)(Og + 8) = o1;
    }
}

extern "C" void kernel_launch(void* const* d_in, const int* in_sizes, int n_in,
                              void* d_out, int out_size, void* d_ws, size_t ws_size,
                              hipStream_t stream) {
    const float* x  = (const float*)d_in[0];
    const float* Wq = (const float*)d_in[1];
    const float* Wk = (const float*)d_in[2];
    const float* Wv = (const float*)d_in[3];
    const float* Wo = (const float*)d_in[4];
    const float* bo = (const float*)d_in[5];
    float* out = (float*)d_out;

    char* ws = (char*)d_ws;
    short* xb  = (short*)(ws + 0);         // 4096x768 bf16
    short* WqT = (short*)(ws + 6291456);
    short* WkT = (short*)(ws + 7471104);
    short* WvT = (short*)(ws + 8650752);
    short* WoT = (short*)(ws + 9830400);
    short* Qb  = (short*)(ws + 11010048);  // [2,12,2048,64] bf16 (pre-scaled)
    short* Kb  = (short*)(ws + 17301504);  // [2,12,2048,64]
    short* VTb = (short*)(ws + 23592960);  // [2,12,64,2048] (transposed)
    short* Ob  = (short*)(ws + 29884416);  // [4096,768] bf16

    k_cvt_x<<<dim3(1536), dim3(256), 0, stream>>>(x, xb);
    k_cvt_whead<<<dim3(12, 12, 3), dim3(256), 0, stream>>>(Wq, Wk, Wv, WqT, WkT, WvT);
    k_cvt_wo<<<dim3(12, 12), dim3(256), 0, stream>>>(Wo, WoT);
    k_gemm<0><<<dim3(6, 32, 3), dim3(256), 0, stream>>>(
        xb, WqT, WkT, WvT, Qb, Kb, VTb, (const float*)nullptr, (float*)nullptr);
    k_attn<<<dim3(24, 16), dim3(512), 0, stream>>>(Qb, Kb, VTb, Ob);
    k_gemm<1><<<dim3(6, 32, 1), dim3(256), 0, stream>>>(
        Ob, WoT, (const short*)nullptr, (const short*)nullptr,
        (short*)nullptr, (short*)nullptr, (short*)nullptr, bo, out);
}

// Round 13
// 100.064 us; speedup vs baseline: 1.1412x; 1.0564x over previous
//
#include <hip/hip_runtime.h>

#define NHEAD 12
#define EMB 768
#define HDD 64
#define SEQ 2048

typedef __attribute__((ext_vector_type(4))) float f32x4;
typedef __attribute__((ext_vector_type(8))) short short8;
typedef __attribute__((ext_vector_type(4))) short short4v;
typedef unsigned int u32;

#define GLL16(g, l)                                                            \
    __builtin_amdgcn_global_load_lds(                                          \
        (const __attribute__((address_space(1))) u32*)(g),                     \
        (__attribute__((address_space(3))) u32*)(l), 16, 0, 0)

static __device__ __forceinline__ short bf16s(float f) {
    unsigned u = __builtin_bit_cast(unsigned, f);
    u = (u + 0x7fffu + ((u >> 16) & 1u)) >> 16;
    return (short)u;
}

// ---- fused converts: one dispatch, block-uniform branch on block range ----
// blocks [0,1536): x f32 -> bf16
// blocks [1536,1968): Wq/Wk/Wv [12][768][64] -> Wt[(h*64+d)][768] bf16
// blocks [1968,2112): Wo [768][768] -> WoT[n][k] bf16
__global__ void k_cvt_all(const float* __restrict__ x, const float* __restrict__ Wq,
                          const float* __restrict__ Wk, const float* __restrict__ Wv,
                          const float* __restrict__ Wo, short* __restrict__ xb,
                          short* __restrict__ WqT, short* __restrict__ WkT,
                          short* __restrict__ WvT, short* __restrict__ WoT) {
    const int bid = blockIdx.x, t = threadIdx.x;
    if (bid < 1536) {
        const int i = (bid * 256 + t) * 8;
        const f32x4* s = (const f32x4*)(x + i);
        f32x4 a = s[0], b = s[1];
        short8 o;
        o[0] = bf16s(a[0]); o[1] = bf16s(a[1]); o[2] = bf16s(a[2]); o[3] = bf16s(a[3]);
        o[4] = bf16s(b[0]); o[5] = bf16s(b[1]); o[6] = bf16s(b[2]); o[7] = bf16s(b[3]);
        *(short8*)(xb + i) = o;
    } else if (bid < 1968) {
        const int idx = bid - 1536;
        const int h = idx % 12, e0 = ((idx / 12) % 12) * 64, z = idx / 144;
        const float* W = z == 0 ? Wq : (z == 1 ? Wk : Wv);
        short* Wt = z == 0 ? WqT : (z == 1 ? WkT : WvT);
        __shared__ float tile[64][65];
        const int r = t >> 2, c0 = (t & 3) * 16;
        const float* src = W + (h * EMB + e0 + r) * HDD + c0;
#pragma unroll
        for (int i = 0; i < 16; ++i) tile[r][c0 + i] = src[i];
        __syncthreads();
        short* dst = Wt + (h * HDD + r) * EMB + e0 + c0;  // r acts as d here
#pragma unroll
        for (int i = 0; i < 16; ++i) dst[i] = bf16s(tile[c0 + i][r]);
    } else {
        const int idx = bid - 1968;
        const int k0 = (idx % 12) * 64, n0 = (idx / 12) * 64;
        __shared__ float tile[64][65];
        const int r = t >> 2, c0 = (t & 3) * 16;
        const float* src = Wo + (k0 + r) * EMB + n0 + c0;
#pragma unroll
        for (int i = 0; i < 16; ++i) tile[r][c0 + i] = src[i];
        __syncthreads();
        short* dst = WoT + (n0 + r) * EMB + k0 + c0;
#pragma unroll
        for (int i = 0; i < 16; ++i) dst[i] = bf16s(tile[c0 + i][r]);
    }
}

// ---- GEMM (r12-proven: m97 structure + BK32 chunk swizzle) ----
// Rule #21: LDS dest linear (global_load_lds), global SOURCE chunk pre-XORed
// with (row>>1)&3, READ applies same XOR.
// MODE 0: z=0 -> Q*0.125 scattered [B,H,S,D]; z=1 -> K scattered;
//         z=2 -> A/B swapped, out = V^T [B,H,D,S] (coalesced).
// MODE 1: f32 out row-major [m][768] + bias.
template <int MODE>
__global__ __launch_bounds__(256) void k_gemm(
        const short* __restrict__ xb, const short* __restrict__ Wt0,
        const short* __restrict__ Wt1, const short* __restrict__ Wt2,
        short* __restrict__ Qo, short* __restrict__ Ko, short* __restrict__ Vo,
        const float* __restrict__ bias, float* __restrict__ Fout) {
    __shared__ alignas(16) short As[128 * 32];
    __shared__ alignas(16) short Bs[128 * 32];
    const int t = threadIdx.x, lane = t & 63, wave = t >> 6;
    const int z = (MODE == 0) ? blockIdx.z : 0;
    const short* Ap;
    const short* Bp;
    int m0, n0;
    if (MODE == 1) {
        Ap = xb; Bp = Wt0; m0 = blockIdx.y * 128; n0 = blockIdx.x * 128;
    } else if (z == 0) {
        Ap = xb; Bp = Wt0; m0 = blockIdx.y * 128; n0 = blockIdx.x * 128;
    } else if (z == 1) {
        Ap = xb; Bp = Wt1; m0 = blockIdx.y * 128; n0 = blockIdx.x * 128;
    } else {  // V^T: A = WvT (768 rows), B = xb (4096 rows)
        Ap = Wt2; Bp = xb; m0 = blockIdx.x * 128; n0 = blockIdx.y * 128;
    }

    const int srow = lane >> 2;
    const int scolSw = ((lane & 3) ^ ((srow >> 1) & 3)) * 8;
    const short* gA = Ap + (long)(m0 + wave * 32 + srow) * EMB + scolSw;
    const short* gB = Bp + (long)(n0 + wave * 32 + srow) * EMB + scolSw;
    short* lA = As + (wave * 32) * 32;
    short* lB = Bs + (wave * 32) * 32;

    const int wm = (wave >> 1) * 64, wn = (wave & 1) * 64;
    const int fr = lane & 15, hi = lane >> 4;
    const int rdoff = (hi ^ ((fr >> 1) & 3)) * 8;  // read-side swizzled chunk

    f32x4 acc[4][4];
#pragma unroll
    for (int i = 0; i < 4; ++i)
#pragma unroll
        for (int j = 0; j < 4; ++j)
#pragma unroll
            for (int e = 0; e < 4; ++e) acc[i][j][e] = 0.f;

    for (int kk = 0; kk < EMB; kk += 32) {
        __syncthreads();
        GLL16(gA + kk, lA);
        GLL16(gA + kk + 16 * EMB, lA + 16 * 32);
        GLL16(gB + kk, lB);
        GLL16(gB + kk + 16 * EMB, lB + 16 * 32);
        __syncthreads();
        short8 af[4], bfq[4];
#pragma unroll
        for (int i = 0; i < 4; ++i)
            af[i] = *(const short8*)(As + (wm + i * 16 + fr) * 32 + rdoff);
#pragma unroll
        for (int j = 0; j < 4; ++j)
            bfq[j] = *(const short8*)(Bs + (wn + j * 16 + fr) * 32 + rdoff);
#pragma unroll
        for (int i = 0; i < 4; ++i)
#pragma unroll
            for (int j = 0; j < 4; ++j)
                acc[i][j] = __builtin_amdgcn_mfma_f32_16x16x32_bf16(af[i], bfq[j], acc[i][j], 0, 0, 0);
    }

    const int r0 = hi * 4;
#pragma unroll
    for (int i = 0; i < 4; ++i) {
#pragma unroll
        for (int j = 0; j < 4; ++j) {
            const int nbase = n0 + wn + j * 16 + fr;
            float bj = 0.f;
            if (MODE == 1) bj = bias[nbase];
#pragma unroll
            for (int r = 0; r < 4; ++r) {
                const int m = m0 + wm + i * 16 + r0 + r;
                float v = acc[i][j][r];
                if (MODE == 0) {
                    if (z == 2) {
                        const int hh = m >> 6, dd = m & 63;
                        const int bb = nbase >> 11, ss = nbase & 2047;
                        Vo[(long)((bb * NHEAD + hh) * HDD + dd) * SEQ + ss] = bf16s(v);
                    } else {
                        const int bb = m >> 11, ss = m & 2047;
                        const int hh = nbase >> 6, dd = nbase & 63;
                        short* Dst = (z == 0) ? Qo : Ko;
                        if (z == 0) v *= 0.125f;  // fold 1/sqrt(64) into Q
                        Dst[(long)((bb * NHEAD + hh) * SEQ + ss) * HDD + dd] = bf16s(v);
                    }
                } else {
                    Fout[(long)m * EMB + nbase] = v + bj;
                }
            }
        }
    }
}

// ---- causal flash attention (swapped-operand form) ----
// Round-13: r12-proven chain, re-granularized to 4 waves x 16 q-rows
// (QBLK=64) -> grid (24,32) = 768 blocks, 45KB LDS -> 3 blocks/CU.
// Occupancy was grid-limited (384 blocks = 1.5/CU); critical path stays
// 32 sequential tiles while co-residency doubles. 2x K/V HBM re-read is
// free at 4% HBM. Internals byte-identical to r12 per wave.
// Q,K: [B,H,S,64] bf16 (Q pre-scaled by 0.125); VT: [B,H,64,S] -> O [B,S,768] bf16
__global__ __launch_bounds__(256) void k_attn(
        const short* __restrict__ Q, const short* __restrict__ K,
        const short* __restrict__ VT, short* __restrict__ O) {
    __shared__ alignas(16) short Kbuf[2][64 * 72];   // [key][d]
    __shared__ alignas(16) short Vbuf[2][64 * 72];   // [d][key]
    __shared__ alignas(16) short Ps[4][16 * 72];     // per-wave P[q][key]; reused as O buf
    const int bh = blockIdx.x;
    const int h = bh % NHEAD, b = bh / NHEAD;
    const int qs = (int)gridDim.y - 1 - (int)blockIdx.y;  // longest first, 0..31
    const int q0 = qs * 64;
    const int ntile = qs + 1;
    const int t = threadIdx.x, lane = t & 63, wave = t >> 6;
    const long base = (long)(b * NHEAD + h) * SEQ * HDD;
    const short* Qg = Q + base;
    const short* Kg = K + base;
    const short* Vg = VT + base;  // [64][2048]
    const int fr = lane & 15, hi = lane >> 4, fk = hi * 8, r0 = hi * 4;
    const int wq = q0 + wave * 16;  // this wave's 16 q-rows

    short8 qf[2];
#pragma unroll
    for (int c = 0; c < 2; ++c)
        qf[c] = *(const short8*)(Qg + (long)(wq + fr) * HDD + c * 32 + fk);

    f32x4 oacc[4];  // O^T: row d = dt*16+r0+r, col q = fr
#pragma unroll
    for (int i = 0; i < 4; ++i)
#pragma unroll
        for (int e = 0; e < 4; ++e) oacc[i][e] = 0.f;
    float mrun = -3e38f, lrun = 0.f;

    // staging: 256 threads, two short8 each for K and V per tile
    const int srow = t >> 2, sc = (t & 3) * 16;
    const short* KgS = Kg + (long)srow * HDD + sc;
    const short* VgS = Vg + (long)srow * SEQ + sc;
    short* Pw = &Ps[wave][0];

    // prologue: tile 0 -> buf0; prefetch tile 1 into regs
    short8 kv0 = *(const short8*)(KgS);
    short8 kv1 = *(const short8*)(KgS + 8);
    short8 vv0 = *(const short8*)(VgS);
    short8 vv1 = *(const short8*)(VgS + 8);
    *(short8*)(&Kbuf[0][srow * 72 + sc]) = kv0;
    *(short8*)(&Kbuf[0][srow * 72 + sc + 8]) = kv1;
    *(short8*)(&Vbuf[0][srow * 72 + sc]) = vv0;
    *(short8*)(&Vbuf[0][srow * 72 + sc + 8]) = vv1;
    if (ntile > 1) {
        kv0 = *(const short8*)(KgS + (long)64 * HDD);
        kv1 = *(const short8*)(KgS + (long)64 * HDD + 8);
        vv0 = *(const short8*)(VgS + 64);
        vv1 = *(const short8*)(VgS + 64 + 8);
    }
    __syncthreads();

    for (int kt = 0; kt < ntile; ++kt) {
        const int k0 = kt * 64;
        const int cur = kt & 1;
        if (kt + 1 < ntile) {
            *(short8*)(&Kbuf[cur ^ 1][srow * 72 + sc]) = kv0;
            *(short8*)(&Kbuf[cur ^ 1][srow * 72 + sc + 8]) = kv1;
            *(short8*)(&Vbuf[cur ^ 1][srow * 72 + sc]) = vv0;
            *(short8*)(&Vbuf[cur ^ 1][srow * 72 + sc + 8]) = vv1;
            if (kt + 2 < ntile) {  // issue tile kt+2 loads early
                kv0 = *(const short8*)(KgS + (long)(k0 + 128) * HDD);
                kv1 = *(const short8*)(KgS + (long)(k0 + 128) * HDD + 8);
                vv0 = *(const short8*)(VgS + (k0 + 128));
                vv1 = *(const short8*)(VgS + (k0 + 128) + 8);
            }
        }
        if (k0 <= wq + 15) {  // wave-uniform activity guard
            const short* Ks = &Kbuf[cur][0];
            const short* Vs = &Vbuf[cur][0];

            f32x4 st[4];
#pragma unroll
            for (int nt = 0; nt < 4; ++nt) {
                const short8 kf0 = *(const short8*)(Ks + (nt * 16 + fr) * 72 + fk);
                const short8 kf1 = *(const short8*)(Ks + (nt * 16 + fr) * 72 + 32 + fk);
#pragma unroll
                for (int e = 0; e < 4; ++e) st[nt][e] = 0.f;
                st[nt] = __builtin_amdgcn_mfma_f32_16x16x32_bf16(kf0, qf[0], st[nt], 0, 0, 0);
                st[nt] = __builtin_amdgcn_mfma_f32_16x16x32_bf16(kf1, qf[1], st[nt], 0, 0, 0);
            }

            float p[4][4];
            float pmax = -3e38f;
            if (k0 + 63 > wq) {  // diagonal-overlap tile: causal mask
                const int myq = wq + fr;
#pragma unroll
                for (int nt = 0; nt < 4; ++nt)
#pragma unroll
                    for (int r = 0; r < 4; ++r) {
                        float s = st[nt][r];
                        if (k0 + nt * 16 + r0 + r > myq) s = -3e38f;
                        p[nt][r] = s;
                        pmax = fmaxf(pmax, s);
                    }
            } else {
#pragma unroll
                for (int nt = 0; nt < 4; ++nt)
#pragma unroll
                    for (int r = 0; r < 4; ++r) {
                        p[nt][r] = st[nt][r];
                        pmax = fmaxf(pmax, st[nt][r]);
                    }
            }
            pmax = fmaxf(pmax, __shfl_xor(pmax, 16, 64));
            pmax = fmaxf(pmax, __shfl_xor(pmax, 32, 64));
            const float mnew = fmaxf(mrun, pmax);
            const float corr = __expf(mrun - mnew);
            mrun = mnew;
            float rsum = 0.f;
#pragma unroll
            for (int nt = 0; nt < 4; ++nt)
#pragma unroll
                for (int r = 0; r < 4; ++r) {
                    const float e = __expf(p[nt][r] - mnew);
                    p[nt][r] = e;
                    rsum += e;
                }
            rsum += __shfl_xor(rsum, 16, 64);
            rsum += __shfl_xor(rsum, 32, 64);
            lrun = lrun * corr + rsum;
#pragma unroll
            for (int dt = 0; dt < 4; ++dt)
#pragma unroll
                for (int e = 0; e < 4; ++e) oacc[dt][e] *= corr;

            // P[q][key] -> per-wave LDS, packed b64 (4 contiguous cols)
#pragma unroll
            for (int nt = 0; nt < 4; ++nt) {
                short4v pk;
                pk[0] = bf16s(p[nt][0]);
                pk[1] = bf16s(p[nt][1]);
                pk[2] = bf16s(p[nt][2]);
                pk[3] = bf16s(p[nt][3]);
                *(short4v*)(Pw + fr * 72 + nt * 16 + r0) = pk;
            }

            // O^T += V^T P^T
#pragma unroll
            for (int kc = 0; kc < 2; ++kc) {
                const short8 pf = *(const short8*)(Pw + fr * 72 + kc * 32 + fk);
#pragma unroll
                for (int dt = 0; dt < 4; ++dt) {
                    const short8 vf = *(const short8*)(Vs + (dt * 16 + fr) * 72 + kc * 32 + fk);
                    oacc[dt] = __builtin_amdgcn_mfma_f32_16x16x32_bf16(vf, pf, oacc[dt], 0, 0, 0);
                }
            }
        }
        __syncthreads();  // buf[cur^1] writes visible; buf[cur] reads done
    }

    // transpose O^T back via LDS (Ps reused as flat [64][72]) and store
    short* Os = &Ps[0][0];
    const float iv = 1.0f / lrun;
#pragma unroll
    for (int dt = 0; dt < 4; ++dt)
#pragma unroll
        for (int r = 0; r < 4; ++r)
            Os[(wave * 16 + fr) * 72 + dt * 16 + r0 + r] = bf16s(oacc[dt][r] * iv);
    __syncthreads();
    {
        const int row = t >> 2, c0 = (t & 3) * 16;
        const short8 o0 = *(const short8*)(Os + row * 72 + c0);
        const short8 o1 = *(const short8*)(Os + row * 72 + c0 + 8);
        short* Og = O + (long)(b * SEQ + q0 + row) * EMB + h * HDD + c0;
        *(short8*)Og = o0;
        *(short8*)(Og + 8) = o1;
    }
}

extern "C" void kernel_launch(void* const* d_in, const int* in_sizes, int n_in,
                              void* d_out, int out_size, void* d_ws, size_t ws_size,
                              hipStream_t stream) {
    const float* x  = (const float*)d_in[0];
    const float* Wq = (const float*)d_in[1];
    const float* Wk = (const float*)d_in[2];
    const float* Wv = (const float*)d_in[3];
    const float* Wo = (const float*)d_in[4];
    const float* bo = (const float*)d_in[5];
    float* out = (float*)d_out;

    char* ws = (char*)d_ws;
    short* xb  = (short*)(ws + 0);         // 4096x768 bf16
    short* WqT = (short*)(ws + 6291456);
    short* WkT = (short*)(ws + 7471104);
    short* WvT = (short*)(ws + 8650752);
    short* WoT = (short*)(ws + 9830400);
    short* Qb  = (short*)(ws + 11010048);  // [2,12,2048,64] bf16 (pre-scaled)
    short* Kb  = (short*)(ws + 17301504);  // [2,12,2048,64]
    short* VTb = (short*)(ws + 23592960);  // [2,12,64,2048] (transposed)
    short* Ob  = (short*)(ws + 29884416);  // [4096,768] bf16

    k_cvt_all<<<dim3(2112), dim3(256), 0, stream>>>(
        x, Wq, Wk, Wv, Wo, xb, WqT, WkT, WvT, WoT);
    k_gemm<0><<<dim3(6, 32, 3), dim3(256), 0, stream>>>(
        xb, WqT, WkT, WvT, Qb, Kb, VTb, (const float*)nullptr, (float*)nullptr);
    k_attn<<<dim3(24, 32), dim3(256), 0, stream>>>(Qb, Kb, VTb, Ob);
    k_gemm<1><<<dim3(6, 32, 1), dim3(256), 0, stream>>>(
        Ob, WoT, (const short*)nullptr, (const short*)nullptr,
        (short*)nullptr, (short*)nullptr, (short*)nullptr, bo, out);
}

// Round 15
// 95.709 us; speedup vs baseline: 1.1931x; 1.0455x over previous
//
#include <hip/hip_runtime.h>

#define NHEAD 12
#define EMB 768
#define HDD 64
#define SEQ 2048

typedef __attribute__((ext_vector_type(4))) float f32x4;
typedef __attribute__((ext_vector_type(8))) short short8;
typedef __attribute__((ext_vector_type(4))) short short4v;
typedef unsigned int u32;

#define GLL16(g, l)                                                            \
    __builtin_amdgcn_global_load_lds(                                          \
        (const __attribute__((address_space(1))) u32*)(g),                     \
        (__attribute__((address_space(3))) u32*)(l), 16, 0, 0)

static __device__ __forceinline__ short bf16s(float f) {
    unsigned u = __builtin_bit_cast(unsigned, f);
    u = (u + 0x7fffu + ((u >> 16) & 1u)) >> 16;
    return (short)u;
}
static __device__ __forceinline__ float bf2f(short s) {
    unsigned u = ((unsigned)(unsigned short)s) << 16;
    return __builtin_bit_cast(float, u);
}

// ---- fused converts: one dispatch, block-uniform branch on block range ----
__global__ void k_cvt_all(const float* __restrict__ x, const float* __restrict__ Wq,
                          const float* __restrict__ Wk, const float* __restrict__ Wv,
                          const float* __restrict__ Wo, short* __restrict__ xb,
                          short* __restrict__ WqT, short* __restrict__ WkT,
                          short* __restrict__ WvT, short* __restrict__ WoT) {
    const int bid = blockIdx.x, t = threadIdx.x;
    if (bid < 1536) {
        const int i = (bid * 256 + t) * 8;
        const f32x4* s = (const f32x4*)(x + i);
        f32x4 a = s[0], b = s[1];
        short8 o;
        o[0] = bf16s(a[0]); o[1] = bf16s(a[1]); o[2] = bf16s(a[2]); o[3] = bf16s(a[3]);
        o[4] = bf16s(b[0]); o[5] = bf16s(b[1]); o[6] = bf16s(b[2]); o[7] = bf16s(b[3]);
        *(short8*)(xb + i) = o;
    } else if (bid < 1968) {
        const int idx = bid - 1536;
        const int h = idx % 12, e0 = ((idx / 12) % 12) * 64, z = idx / 144;
        const float* W = z == 0 ? Wq : (z == 1 ? Wk : Wv);
        short* Wt = z == 0 ? WqT : (z == 1 ? WkT : WvT);
        __shared__ float tile[64][65];
        const int r = t >> 2, c0 = (t & 3) * 16;
        const float* src = W + (h * EMB + e0 + r) * HDD + c0;
#pragma unroll
        for (int i = 0; i < 16; ++i) tile[r][c0 + i] = src[i];
        __syncthreads();
        short* dst = Wt + (h * HDD + r) * EMB + e0 + c0;  // r acts as d here
#pragma unroll
        for (int i = 0; i < 16; ++i) dst[i] = bf16s(tile[c0 + i][r]);
    } else {
        const int idx = bid - 1968;
        const int k0 = (idx % 12) * 64, n0 = (idx / 12) * 64;
        __shared__ float tile[64][65];
        const int r = t >> 2, c0 = (t & 3) * 16;
        const float* src = Wo + (k0 + r) * EMB + n0 + c0;
#pragma unroll
        for (int i = 0; i < 16; ++i) tile[r][c0 + i] = src[i];
        __syncthreads();
        short* dst = WoT + (n0 + r) * EMB + k0 + c0;
#pragma unroll
        for (int i = 0; i < 16; ++i) dst[i] = bf16s(tile[c0 + i][r]);
    }
}

// ---- GEMM (r12/r13-proven: m97 structure + BK32 chunk swizzle) ----
template <int MODE>
__global__ __launch_bounds__(256) void k_gemm(
        const short* __restrict__ xb, const short* __restrict__ Wt0,
        const short* __restrict__ Wt1, const short* __restrict__ Wt2,
        short* __restrict__ Qo, short* __restrict__ Ko, short* __restrict__ Vo,
        const float* __restrict__ bias, float* __restrict__ Fout) {
    __shared__ alignas(16) short As[128 * 32];
    __shared__ alignas(16) short Bs[128 * 32];
    const int t = threadIdx.x, lane = t & 63, wave = t >> 6;
    const int z = (MODE == 0) ? blockIdx.z : 0;
    const short* Ap;
    const short* Bp;
    int m0, n0;
    if (MODE == 1) {
        Ap = xb; Bp = Wt0; m0 = blockIdx.y * 128; n0 = blockIdx.x * 128;
    } else if (z == 0) {
        Ap = xb; Bp = Wt0; m0 = blockIdx.y * 128; n0 = blockIdx.x * 128;
    } else if (z == 1) {
        Ap = xb; Bp = Wt1; m0 = blockIdx.y * 128; n0 = blockIdx.x * 128;
    } else {  // V^T: A = WvT (768 rows), B = xb (4096 rows)
        Ap = Wt2; Bp = xb; m0 = blockIdx.x * 128; n0 = blockIdx.y * 128;
    }

    const int srow = lane >> 2;
    const int scolSw = ((lane & 3) ^ ((srow >> 1) & 3)) * 8;
    const short* gA = Ap + (long)(m0 + wave * 32 + srow) * EMB + scolSw;
    const short* gB = Bp + (long)(n0 + wave * 32 + srow) * EMB + scolSw;
    short* lA = As + (wave * 32) * 32;
    short* lB = Bs + (wave * 32) * 32;

    const int wm = (wave >> 1) * 64, wn = (wave & 1) * 64;
    const int fr = lane & 15, hi = lane >> 4;
    const int rdoff = (hi ^ ((fr >> 1) & 3)) * 8;

    f32x4 acc[4][4];
#pragma unroll
    for (int i = 0; i < 4; ++i)
#pragma unroll
        for (int j = 0; j < 4; ++j)
#pragma unroll
            for (int e = 0; e < 4; ++e) acc[i][j][e] = 0.f;

    for (int kk = 0; kk < EMB; kk += 32) {
        __syncthreads();
        GLL16(gA + kk, lA);
        GLL16(gA + kk + 16 * EMB, lA + 16 * 32);
        GLL16(gB + kk, lB);
        GLL16(gB + kk + 16 * EMB, lB + 16 * 32);
        __syncthreads();
        short8 af[4], bfq[4];
#pragma unroll
        for (int i = 0; i < 4; ++i)
            af[i] = *(const short8*)(As + (wm + i * 16 + fr) * 32 + rdoff);
#pragma unroll
        for (int j = 0; j < 4; ++j)
            bfq[j] = *(const short8*)(Bs + (wn + j * 16 + fr) * 32 + rdoff);
#pragma unroll
        for (int i = 0; i < 4; ++i)
#pragma unroll
            for (int j = 0; j < 4; ++j)
                acc[i][j] = __builtin_amdgcn_mfma_f32_16x16x32_bf16(af[i], bfq[j], acc[i][j], 0, 0, 0);
    }

    const int r0 = hi * 4;
#pragma unroll
    for (int i = 0; i < 4; ++i) {
#pragma unroll
        for (int j = 0; j < 4; ++j) {
            const int nbase = n0 + wn + j * 16 + fr;
            float bj = 0.f;
            if (MODE == 1) bj = bias[nbase];
#pragma unroll
            for (int r = 0; r < 4; ++r) {
                const int m = m0 + wm + i * 16 + r0 + r;
                float v = acc[i][j][r];
                if (MODE == 0) {
                    if (z == 2) {
                        const int hh = m >> 6, dd = m & 63;
                        const int bb = nbase >> 11, ss = nbase & 2047;
                        Vo[(long)((bb * NHEAD + hh) * HDD + dd) * SEQ + ss] = bf16s(v);
                    } else {
                        const int bb = m >> 11, ss = m & 2047;
                        const int hh = nbase >> 6, dd = nbase & 63;
                        short* Dst = (z == 0) ? Qo : Ko;
                        if (z == 0) v *= 0.125f;  // fold 1/sqrt(64) into Q
                        Dst[(long)((bb * NHEAD + hh) * SEQ + ss) * HDD + dd] = bf16s(v);
                    }
                } else {
                    Fout[(long)m * EMB + nbase] = v + bj;
                }
            }
        }
    }
}

// ---- causal flash attention with SPLIT-K over key chunks ----
// r15 fix: partial-U write was missing the wave*16 q-offset (all 4 waves
// clobbered cols 0-15; cols 16-63 held stale ws bytes -> finite ~0.05 err).
// Everything else identical to r14 (inner loop = r12/r13-proven).
__global__ __launch_bounds__(256) void k_attn(
        const short* __restrict__ Q, const short* __restrict__ K,
        const short* __restrict__ VT, short* __restrict__ O,
        short* __restrict__ Ub, float* __restrict__ Mb, float* __restrict__ Lb) {
    __shared__ alignas(16) short Kbuf[2][64 * 72];   // [key][d]
    __shared__ alignas(16) short Vbuf[2][64 * 72];   // [d][key]
    __shared__ alignas(16) short Ps[4][16 * 72];     // per-wave P; reused as O buf
    const int bh = blockIdx.x;
    const int h = bh % NHEAD, b = bh / NHEAD;
    const int yy = blockIdx.y;
    int qs, kb, ke, chunk, split;
    if (yy < 16)      { qs = 16 + yy; kb = 0;  ke = 16;     chunk = 0; split = 1; }
    else if (yy < 32) { qs = yy;      kb = 16; ke = qs + 1; chunk = 1; split = 1; }
    else              { qs = 47 - yy; kb = 0;  ke = qs + 1; chunk = 0; split = 0; }
    const int q0 = qs * 64;
    const int t = threadIdx.x, lane = t & 63, wave = t >> 6;
    const long base = (long)(b * NHEAD + h) * SEQ * HDD;
    const short* Qg = Q + base;
    const short* Kg = K + base;
    const short* Vg = VT + base;  // [64][2048]
    const int fr = lane & 15, hi = lane >> 4, fk = hi * 8, r0 = hi * 4;
    const int wq = q0 + wave * 16;  // this wave's 16 q-rows

    short8 qf[2];
#pragma unroll
    for (int c = 0; c < 2; ++c)
        qf[c] = *(const short8*)(Qg + (long)(wq + fr) * HDD + c * 32 + fk);

    f32x4 oacc[4];  // O^T (unnormalized U^T): row d = dt*16+r0+r, col q = fr
#pragma unroll
    for (int i = 0; i < 4; ++i)
#pragma unroll
        for (int e = 0; e < 4; ++e) oacc[i][e] = 0.f;
    float mrun = -3e38f, lrun = 0.f;

    // staging: 256 threads, two short8 each for K and V per tile
    const int srow = t >> 2, sc = (t & 3) * 16;
    const short* KgS = Kg + (long)srow * HDD + sc;
    const short* VgS = Vg + (long)srow * SEQ + sc;
    short* Pw = &Ps[wave][0];

    // prologue: tile kb -> buf0; prefetch tile kb+1 into regs
    short8 kv0 = *(const short8*)(KgS + (long)(kb * 64) * HDD);
    short8 kv1 = *(const short8*)(KgS + (long)(kb * 64) * HDD + 8);
    short8 vv0 = *(const short8*)(VgS + kb * 64);
    short8 vv1 = *(const short8*)(VgS + kb * 64 + 8);
    *(short8*)(&Kbuf[0][srow * 72 + sc]) = kv0;
    *(short8*)(&Kbuf[0][srow * 72 + sc + 8]) = kv1;
    *(short8*)(&Vbuf[0][srow * 72 + sc]) = vv0;
    *(short8*)(&Vbuf[0][srow * 72 + sc + 8]) = vv1;
    if (ke - kb > 1) {
        kv0 = *(const short8*)(KgS + (long)(kb * 64 + 64) * HDD);
        kv1 = *(const short8*)(KgS + (long)(kb * 64 + 64) * HDD + 8);
        vv0 = *(const short8*)(VgS + kb * 64 + 64);
        vv1 = *(const short8*)(VgS + kb * 64 + 64 + 8);
    }
    __syncthreads();

    for (int kt = kb; kt < ke; ++kt) {
        const int k0 = kt * 64;
        const int cur = (kt - kb) & 1;
        if (kt + 1 < ke) {
            *(short8*)(&Kbuf[cur ^ 1][srow * 72 + sc]) = kv0;
            *(short8*)(&Kbuf[cur ^ 1][srow * 72 + sc + 8]) = kv1;
            *(short8*)(&Vbuf[cur ^ 1][srow * 72 + sc]) = vv0;
            *(short8*)(&Vbuf[cur ^ 1][srow * 72 + sc + 8]) = vv1;
            if (kt + 2 < ke) {  // issue tile kt+2 loads early
                kv0 = *(const short8*)(KgS + (long)(k0 + 128) * HDD);
                kv1 = *(const short8*)(KgS + (long)(k0 + 128) * HDD + 8);
                vv0 = *(const short8*)(VgS + (k0 + 128));
                vv1 = *(const short8*)(VgS + (k0 + 128) + 8);
            }
        }
        if (k0 <= wq + 15) {  // wave-uniform activity guard
            const short* Ks = &Kbuf[cur][0];
            const short* Vs = &Vbuf[cur][0];

            f32x4 st[4];
#pragma unroll
            for (int nt = 0; nt < 4; ++nt) {
                const short8 kf0 = *(const short8*)(Ks + (nt * 16 + fr) * 72 + fk);
                const short8 kf1 = *(const short8*)(Ks + (nt * 16 + fr) * 72 + 32 + fk);
#pragma unroll
                for (int e = 0; e < 4; ++e) st[nt][e] = 0.f;
                st[nt] = __builtin_amdgcn_mfma_f32_16x16x32_bf16(kf0, qf[0], st[nt], 0, 0, 0);
                st[nt] = __builtin_amdgcn_mfma_f32_16x16x32_bf16(kf1, qf[1], st[nt], 0, 0, 0);
            }

            float p[4][4];
            float pmax = -3e38f;
            if (k0 + 63 > wq) {  // diagonal-overlap tile: causal mask
                const int myq = wq + fr;
#pragma unroll
                for (int nt = 0; nt < 4; ++nt)
#pragma unroll
                    for (int r = 0; r < 4; ++r) {
                        float s = st[nt][r];
                        if (k0 + nt * 16 + r0 + r > myq) s = -3e38f;
                        p[nt][r] = s;
                        pmax = fmaxf(pmax, s);
                    }
            } else {
#pragma unroll
                for (int nt = 0; nt < 4; ++nt)
#pragma unroll
                    for (int r = 0; r < 4; ++r) {
                        p[nt][r] = st[nt][r];
                        pmax = fmaxf(pmax, st[nt][r]);
                    }
            }
            pmax = fmaxf(pmax, __shfl_xor(pmax, 16, 64));
            pmax = fmaxf(pmax, __shfl_xor(pmax, 32, 64));
            const float mnew = fmaxf(mrun, pmax);
            const float corr = __expf(mrun - mnew);
            mrun = mnew;
            float rsum = 0.f;
#pragma unroll
            for (int nt = 0; nt < 4; ++nt)
#pragma unroll
                for (int r = 0; r < 4; ++r) {
                    const float e = __expf(p[nt][r] - mnew);
                    p[nt][r] = e;
                    rsum += e;
                }
            rsum += __shfl_xor(rsum, 16, 64);
            rsum += __shfl_xor(rsum, 32, 64);
            lrun = lrun * corr + rsum;
#pragma unroll
            for (int dt = 0; dt < 4; ++dt)
#pragma unroll
                for (int e = 0; e < 4; ++e) oacc[dt][e] *= corr;

            // P[q][key] -> per-wave LDS, packed b64 (4 contiguous cols)
#pragma unroll
            for (int nt = 0; nt < 4; ++nt) {
                short4v pk;
                pk[0] = bf16s(p[nt][0]);
                pk[1] = bf16s(p[nt][1]);
                pk[2] = bf16s(p[nt][2]);
                pk[3] = bf16s(p[nt][3]);
                *(short4v*)(Pw + fr * 72 + nt * 16 + r0) = pk;
            }

            // O^T += V^T P^T
#pragma unroll
            for (int kc = 0; kc < 2; ++kc) {
                const short8 pf = *(const short8*)(Pw + fr * 72 + kc * 32 + fk);
#pragma unroll
                for (int dt = 0; dt < 4; ++dt) {
                    const short8 vf = *(const short8*)(Vs + (dt * 16 + fr) * 72 + kc * 32 + fk);
                    oacc[dt] = __builtin_amdgcn_mfma_f32_16x16x32_bf16(vf, pf, oacc[dt], 0, 0, 0);
                }
            }
        }
        __syncthreads();  // buf[cur^1] writes visible; buf[cur] reads done
    }

    if (split) {
        // partial epilogue: U^T bf16 [64 d][64 q] + per-row m,l (f32)
        // q column = wave*16 + fr (strip-local) — r14 bug was missing wave*16
        const int pidx = (bh * 16 + (qs - 16)) * 2 + chunk;
        short* Up = Ub + pidx * 4096;
#pragma unroll
        for (int dt = 0; dt < 4; ++dt)
#pragma unroll
            for (int r = 0; r < 4; ++r)
                Up[(dt * 16 + r0 + r) * 64 + wave * 16 + fr] = bf16s(oacc[dt][r]);
        if (lane < 16) {
            Mb[pidx * 64 + wave * 16 + lane] = mrun;
            Lb[pidx * 64 + wave * 16 + lane] = lrun;
        }
        return;
    }

    // direct epilogue: transpose O^T back via LDS (Ps reused) and store
    short* Os = &Ps[0][0];
    const float iv = 1.0f / lrun;
#pragma unroll
    for (int dt = 0; dt < 4; ++dt)
#pragma unroll
        for (int r = 0; r < 4; ++r)
            Os[(wave * 16 + fr) * 72 + dt * 16 + r0 + r] = bf16s(oacc[dt][r] * iv);
    __syncthreads();
    {
        const int row = t >> 2, c0 = (t & 3) * 16;
        const short8 o0 = *(const short8*)(Os + row * 72 + c0);
        const short8 o1 = *(const short8*)(Os + row * 72 + c0 + 8);
        short* Og = O + (long)(b * SEQ + q0 + row) * EMB + h * HDD + c0;
        *(short8*)Og = o0;
        *(short8*)(Og + 8) = o1;
    }
}

// ---- split-K merge: O = (U1 e^{m1-m} + U2 e^{m2-m}) / (l1 e^{m1-m} + l2 e^{m2-m}) ----
__global__ __launch_bounds__(256) void k_merge(
        const short* __restrict__ Ub, const float* __restrict__ Mb,
        const float* __restrict__ Lb, short* __restrict__ O) {
    __shared__ float aS[64], bS[64], iL[64];
    __shared__ short tile[64 * 72];
    const int bid = blockIdx.x;
    const int bh = bid >> 4, sidx = bid & 15;
    const int h = bh % NHEAD, b = bh / NHEAD;
    const int q0 = (16 + sidx) * 64;
    const int p0 = (bh * 16 + sidx) * 2, p1 = p0 + 1;
    const int t = threadIdx.x;
    if (t < 64) {
        const float m1 = Mb[p0 * 64 + t], m2 = Mb[p1 * 64 + t];
        const float l1 = Lb[p0 * 64 + t], l2 = Lb[p1 * 64 + t];
        const float m = fmaxf(m1, m2);
        const float a = __expf(m1 - m), bb = __expf(m2 - m);
        aS[t] = a;
        bS[t] = bb;
        iL[t] = 1.0f / (l1 * a + l2 * bb);
    }
    __syncthreads();
    {
        const int d = t >> 2, qg = (t & 3) * 16;
        const short8 u1a = *(const short8*)(Ub + p0 * 4096 + d * 64 + qg);
        const short8 u1b = *(const short8*)(Ub + p0 * 4096 + d * 64 + qg + 8);
        const short8 u2a = *(const short8*)(Ub + p1 * 4096 + d * 64 + qg);
        const short8 u2b = *(const short8*)(Ub + p1 * 4096 + d * 64 + qg + 8);
#pragma unroll
        for (int i = 0; i < 8; ++i) {
            const int q = qg + i;
            tile[q * 72 + d] = bf16s((bf2f(u1a[i]) * aS[q] + bf2f(u2a[i]) * bS[q]) * iL[q]);
        }
#pragma unroll
        for (int i = 0; i < 8; ++i) {
            const int q = qg + 8 + i;
            tile[q * 72 + d] = bf16s((bf2f(u1b[i]) * aS[q] + bf2f(u2b[i]) * bS[q]) * iL[q]);
        }
    }
    __syncthreads();
    {
        const int q = t >> 2, dg = (t & 3) * 16;
        const short8 o0 = *(const short8*)(tile + q * 72 + dg);
        const short8 o1 = *(const short8*)(tile + q * 72 + dg + 8);
        short* Og = O + (long)(b * SEQ + q0 + q) * EMB + h * HDD + dg;
        *(short8*)Og = o0;
        *(short8*)(Og + 8) = o1;
    }
}

extern "C" void kernel_launch(void* const* d_in, const int* in_sizes, int n_in,
                              void* d_out, int out_size, void* d_ws, size_t ws_size,
                              hipStream_t stream) {
    const float* x  = (const float*)d_in[0];
    const float* Wq = (const float*)d_in[1];
    const float* Wk = (const float*)d_in[2];
    const float* Wv = (const float*)d_in[3];
    const float* Wo = (const float*)d_in[4];
    const float* bo = (const float*)d_in[5];
    float* out = (float*)d_out;

    char* ws = (char*)d_ws;
    short* xb  = (short*)(ws + 0);         // 4096x768 bf16 (dead after gemm0)
    short* WqT = (short*)(ws + 6291456);   // (dead after gemm0)
    short* WkT = (short*)(ws + 7471104);
    short* WvT = (short*)(ws + 8650752);
    short* WoT = (short*)(ws + 9830400);
    short* Qb  = (short*)(ws + 11010048);  // [2,12,2048,64] bf16 (pre-scaled)
    short* Kb  = (short*)(ws + 17301504);  // [2,12,2048,64]
    short* VTb = (short*)(ws + 23592960);  // [2,12,64,2048] (transposed)
    short* Ob  = (short*)(ws + 29884416);  // [4096,768] bf16
    // split-K partials overlay the dead xb/WqT regions during attn+merge:
    short* Ub  = (short*)(ws + 0);         // 768 x [64][64] bf16 = 6,291,456 B
    float* Mb  = (float*)(ws + 6291456);   // 768 x 64 f32 = 196,608 B
    float* Lb  = (float*)(ws + 6488064);   // 768 x 64 f32 = 196,608 B (< 7,471,104)

    k_cvt_all<<<dim3(2112), dim3(256), 0, stream>>>(
        x, Wq, Wk, Wv, Wo, xb, WqT, WkT, WvT, WoT);
    k_gemm<0><<<dim3(6, 32, 3), dim3(256), 0, stream>>>(
        xb, WqT, WkT, WvT, Qb, Kb, VTb, (const float*)nullptr, (float*)nullptr);
    k_attn<<<dim3(24, 48), dim3(256), 0, stream>>>(Qb, Kb, VTb, Ob, Ub, Mb, Lb);
    k_merge<<<dim3(384), dim3(256), 0, stream>>>(Ub, Mb, Lb, Ob);
    k_gemm<1><<<dim3(6, 32, 1), dim3(256), 0, stream>>>(
        Ob, WoT, (const short*)nullptr, (const short*)nullptr,
        (short*)nullptr, (short*)nullptr, (short*)nullptr, bo, out);
}